// Round 1
// baseline (710.511 us; speedup 1.0000x reference)
//
#include <hip/hip_runtime.h>

// Problem constants (match reference setup_inputs)
#define NN 50000
#define EE 800000
#define DD 256
#define LL 3
#define GG 512
#define MPAD 50048  // 782 * 64, GEMM row-tile padding

typedef __attribute__((ext_vector_type(4))) _Float16 half4;
typedef __attribute__((ext_vector_type(8))) _Float16 half8;
typedef __attribute__((ext_vector_type(16))) float floatx16;

// ---------------------------------------------------------------------------
// fp32 -> fp16 convert of x (one-time; h lives in fp16 from then on).
// ---------------------------------------------------------------------------
__global__ void k_convert(const float* __restrict__ x, _Float16* __restrict__ h16) {
    int i = blockIdx.x * 256 + threadIdx.x;  // float4 groups
    if (i >= NN * DD / 4) return;
    float4 v = ((const float4*)x)[i];
    half4 o;
    o.x = (_Float16)v.x; o.y = (_Float16)v.y; o.z = (_Float16)v.z; o.w = (_Float16)v.w;
    ((half4*)h16)[i] = o;
}

// ---------------------------------------------------------------------------
// CSR build: histogram -> 3-kernel parallel scan -> scatter
// ---------------------------------------------------------------------------
__global__ void k_hist(const int* __restrict__ dst, int* __restrict__ deg, int e) {
    int i = blockIdx.x * blockDim.x + threadIdx.x;
    if (i < e) atomicAdd(&deg[dst[i]], 1);
}

__global__ void k_scan1(const int* __restrict__ deg, int* __restrict__ rp,
                        int* __restrict__ bsum, int n) {
    __shared__ int s[1024];
    int t = threadIdx.x;
    int i = blockIdx.x * 1024 + t;
    int v = (i < n) ? deg[i] : 0;
    s[t] = v;
    __syncthreads();
    for (int off = 1; off < 1024; off <<= 1) {
        int tmp = (t >= off) ? s[t - off] : 0;
        __syncthreads();
        s[t] += tmp;
        __syncthreads();
    }
    if (i < n) rp[i] = s[t] - v;          // local exclusive
    if (t == 1023) bsum[blockIdx.x] = s[1023];
}

__global__ void k_scan2(int* __restrict__ bsum, int nb, int* __restrict__ total_out) {
    int lane = threadIdx.x & 63;
    int v = (lane < nb) ? bsum[lane] : 0;
    int orig = v;
    for (int off = 1; off < 64; off <<= 1) {
        int u = __shfl_up(v, off);
        if (lane >= off) v += u;
    }
    if (lane < nb) bsum[lane] = v - orig;  // exclusive block offsets
    if (lane == 63) *total_out = v;        // grand total -> row_ptr[N]
}

__global__ void k_scan3(int* __restrict__ rp, const int* __restrict__ bsum,
                        int* __restrict__ cursor, int n) {
    int i = blockIdx.x * 1024 + threadIdx.x;
    if (i < n) {
        int v = rp[i] + bsum[blockIdx.x];
        rp[i] = v;
        cursor[i] = v;
    }
}

__global__ void k_scatter(const int* __restrict__ src, const int* __restrict__ dst,
                          int* __restrict__ cursor, int* __restrict__ csr_src, int e) {
    int i = blockIdx.x * blockDim.x + threadIdx.x;
    if (i < e) {
        int d = dst[i];
        int pos = atomicAdd(&cursor[d], 1);
        csr_src[pos] = src[i];
    }
}

// ---------------------------------------------------------------------------
// Pre-pack W (fp32 [256,256], k-major) into fp16 MFMA B-fragments for
// mfma_f32_32x32x16_f16. Fragment (ks,nt): lane l holds
// B[ks*16 + (l>>5)*8 + j][nt*32 + (l&31)], j=0..7, 16B contiguous per lane.
// ---------------------------------------------------------------------------
__global__ void k_wpack(const float* __restrict__ Ws1, const float* __restrict__ Ws2,
                        _Float16* __restrict__ Wp) {
    int tid  = blockIdx.x * 256 + threadIdx.x;  // 6*16*8*64 = 49152
    int lane = tid & 63;
    int nt   = (tid >> 6) & 7;
    int ks   = (tid >> 9) & 15;
    int w    = tid >> 13;
    if (w >= 6) return;
    int l = w >> 1, s = w & 1;
    const float* W = (s == 0 ? Ws1 : Ws2) + (size_t)l * DD * DD;
    int kbase = ks * 16 + (lane >> 5) * 8;
    int n     = nt * 32 + (lane & 31);
    half8 hi;
#pragma unroll
    for (int j = 0; j < 8; ++j) hi[j] = (_Float16)W[(size_t)(kbase + j) * DD + n];
    ((half8*)Wp)[(((size_t)w * 16 + ks) * 8 + nt) * 64 + lane] = hi;
}

// ---------------------------------------------------------------------------
// Fused layer kernel: gather + MLP + pool-accumulate.
//   Phase G: agg[n] = h[n] + sum_{j->n} h[j] for the block's 64 rows,
//            gathered straight into LDS (swizzled fp16 A-tile). Each of the
//            4 waves owns 16 rows; adjacency prefetched lane-parallel then
//            broadcast by __shfl; row loads unrolled 8x for MLP.
//   Phase 1: acc = A @ W1 from LDS (mfma_f32_32x32x16_f16).
//   Phase E1: t = relu(acc+b1) -> SAME LDS buffer (A-tile dead after GEMM1).
//   Phase 2: acc2 = t @ W2.
//   Phase E2: h = relu(acc2+b2) -> h16 (fp16) + node_embed (fp32), plus
//            per-graph column partial sums (batch is sorted, so a wave's 32
//            rows span 1-2 graphs) atomically added into gsum [G,768].
// LDS stays 32 KB (A-tile and t time-share one buffer; 3 barriers).
// ---------------------------------------------------------------------------
__global__ __launch_bounds__(256) void k_mlp(
        const _Float16* __restrict__ h,    // layer input [MPAD, 256]
        const int* __restrict__ row_ptr,
        const int* __restrict__ csr_src,
        const int* __restrict__ batch,
        const _Float16* __restrict__ Wp1, const float* __restrict__ b1,
        const _Float16* __restrict__ Wp2, const float* __restrict__ b2,
        _Float16* __restrict__ Hout,       // layer output [MPAD, 256] (!= h)
        float* __restrict__ Fout,          // node_embed + l*256, row stride 768
        float* __restrict__ Gout) {        // gsum + l*256, row stride 768
    __shared__ _Float16 t_lds[64 * 256];   // 32 KB, A-tile then t
    __shared__ int batch_s[64];
    int t    = threadIdx.x;
    int lane = t & 63;
    int w    = t >> 6;
    int wm   = w >> 1, wn = w & 1;
    int r0   = blockIdx.x * 64;

    if (t < 64) {
        int r = r0 + t;
        batch_s[t] = (r < NN) ? batch[r] : 0x7fffffff;
    }

    // ---- Phase G: gather 16 rows per wave into swizzled LDS A-tile ----
    for (int i = 0; i < 16; ++i) {
        int lr = w * 16 + i;
        int n  = r0 + lr;
        half4 acc;
        acc.x = acc.y = acc.z = acc.w = (_Float16)0;
        if (n < NN) {
            int beg = row_ptr[n], end = row_ptr[n + 1];
            int deg = end - beg;
            // lane-parallel adjacency prefetch (covers first 64 edges)
            int idx = (lane < deg) ? csr_src[beg + lane] : 0;
            acc = ((const half4*)(h + (size_t)n * DD))[lane];
            int d64 = deg < 64 ? deg : 64;
            int j = 0;
            for (; j + 8 <= d64; j += 8) {
                int s0 = __shfl(idx, j + 0);
                int s1 = __shfl(idx, j + 1);
                int s2 = __shfl(idx, j + 2);
                int s3 = __shfl(idx, j + 3);
                int s4 = __shfl(idx, j + 4);
                int s5 = __shfl(idx, j + 5);
                int s6 = __shfl(idx, j + 6);
                int s7 = __shfl(idx, j + 7);
                half4 v0 = ((const half4*)(h + (size_t)s0 * DD))[lane];
                half4 v1 = ((const half4*)(h + (size_t)s1 * DD))[lane];
                half4 v2 = ((const half4*)(h + (size_t)s2 * DD))[lane];
                half4 v3 = ((const half4*)(h + (size_t)s3 * DD))[lane];
                half4 v4 = ((const half4*)(h + (size_t)s4 * DD))[lane];
                half4 v5 = ((const half4*)(h + (size_t)s5 * DD))[lane];
                half4 v6 = ((const half4*)(h + (size_t)s6 * DD))[lane];
                half4 v7 = ((const half4*)(h + (size_t)s7 * DD))[lane];
                acc += v0; acc += v1; acc += v2; acc += v3;
                acc += v4; acc += v5; acc += v6; acc += v7;
            }
            for (; j < d64; ++j) {
                int s = __shfl(idx, j);
                acc += ((const half4*)(h + (size_t)s * DD))[lane];
            }
            for (int e2 = beg + 64; e2 < end; ++e2) {  // rare high-degree tail
                int s = csr_src[e2];
                acc += ((const half4*)(h + (size_t)s * DD))[lane];
            }
        }
        // swizzled write: same XOR layout GEMM1/GEMM2 b128 reads expect
        int c0 = lane * 4;
        *(half4*)&t_lds[lr * 256 + ((((c0 >> 3) ^ (lr & 7)) << 3) | (c0 & 7))] = acc;
    }
    __syncthreads();

    // ---- GEMM1: acc = A @ W1 (A fragments from swizzled LDS) ----
    const half8* B1 = (const half8*)Wp1;
    int r = wm * 32 + (lane & 31);

    floatx16 acc[4];
#pragma unroll
    for (int nt = 0; nt < 4; ++nt)
#pragma unroll
        for (int i = 0; i < 16; ++i) acc[nt][i] = 0.0f;

#pragma unroll 4
    for (int ks = 0; ks < 16; ++ks) {
        int kblk = ks * 2 + (lane >> 5);
        half8 a = *(const half8*)&t_lds[r * 256 + ((kblk ^ (r & 7)) << 3)];
#pragma unroll
        for (int nt = 0; nt < 4; ++nt) {
            half8 b = B1[(size_t)(ks * 8 + wn * 4 + nt) * 64 + lane];
            acc[nt] = __builtin_amdgcn_mfma_f32_32x32x16_f16(a, b, acc[nt], 0, 0, 0);
        }
    }
    __syncthreads();  // all waves done reading A-tile before overwrite

    // ---- epilogue 1: t = relu(acc + b1) -> LDS (fp16, swizzled) ----
#pragma unroll
    for (int nt = 0; nt < 4; ++nt) {
        int c  = wn * 128 + nt * 32 + (lane & 31);
        float bv = b1[c];
#pragma unroll
        for (int reg = 0; reg < 16; ++reg) {
            int lr = wm * 32 + (reg & 3) + 8 * (reg >> 2) + 4 * (lane >> 5);
            float v = fmaxf(acc[nt][reg] + bv, 0.0f);
            t_lds[lr * 256 + ((((c >> 3) ^ (lr & 7)) << 3) | (c & 7))] = (_Float16)v;
        }
    }
    __syncthreads();

    // ---- GEMM2: acc2 = t @ W2 (A fragments from swizzled LDS) ----
    const half8* B2 = (const half8*)Wp2;
    floatx16 acc2[4];
#pragma unroll
    for (int nt = 0; nt < 4; ++nt)
#pragma unroll
        for (int i = 0; i < 16; ++i) acc2[nt][i] = 0.0f;

#pragma unroll 4
    for (int ks = 0; ks < 16; ++ks) {
        int kblk = ks * 2 + (lane >> 5);
        half8 a = *(const half8*)&t_lds[r * 256 + ((kblk ^ (r & 7)) << 3)];
#pragma unroll
        for (int nt = 0; nt < 4; ++nt) {
            half8 b = B2[(size_t)(ks * 8 + wn * 4 + nt) * 64 + lane];
            acc2[nt] = __builtin_amdgcn_mfma_f32_32x32x16_f16(a, b, acc2[nt], 0, 0, 0);
        }
    }

    // ---- epilogue 2: h = relu(acc2 + b2) -> fp16 h16 + fp32 node_embed ----
    const int rbase = wm * 32 + 4 * (lane >> 5);
#pragma unroll
    for (int nt = 0; nt < 4; ++nt) {
        int col = wn * 128 + nt * 32 + (lane & 31);
        float bv = b2[col];
#pragma unroll
        for (int reg = 0; reg < 16; ++reg) {
            int rowid = rbase + (reg & 3) + 8 * (reg >> 2);
            int row = r0 + rowid;
            if (row < NN) {
                float v = fmaxf(acc2[nt][reg] + bv, 0.0f);
                Hout[(size_t)row * DD + col] = (_Float16)v;
                Fout[(size_t)row * 768 + col] = v;
            }
        }
    }

    // ---- pool accumulate: per-graph column sums (batch sorted; a wave's
    //      32 rows span ~1-2 graphs). Cross-half merge by shfl_xor(32),
    //      then one atomicAdd per (graph, col) partial.
    int lastid = NN - 1 - r0 - wm * 32;
    if (lastid >= 0) {
        if (lastid > 31) lastid = 31;
        int g0 = batch_s[wm * 32];
        int g1 = batch_s[wm * 32 + lastid];
        for (int g = g0; g <= g1; ++g) {
#pragma unroll
            for (int nt = 0; nt < 4; ++nt) {
                int col = wn * 128 + nt * 32 + (lane & 31);
                float bv = b2[col];
                float s = 0.0f;
#pragma unroll
                for (int reg = 0; reg < 16; ++reg) {
                    int rowid = rbase + (reg & 3) + 8 * (reg >> 2);
                    if (batch_s[rowid] == g)
                        s += fmaxf(acc2[nt][reg] + bv, 0.0f);
                }
                s += __shfl_xor(s, 32);
                if (lane < 32)
                    atomicAdd(&Gout[(size_t)g * 768 + col], s);
            }
        }
    }
}

// ---------------------------------------------------------------------------
// Finalize pool: graph_embed = gsum / count. One block per graph.
// ---------------------------------------------------------------------------
__global__ void k_pool_final(const float* __restrict__ gsum,
                             const int* __restrict__ batch,
                             float* __restrict__ graph_embed) {
    int g = blockIdx.x;
    int t = threadIdx.x;  // 0..191
    int start, end;
    { int l = 0, h = NN; while (l < h) { int m = (l + h) >> 1; if (batch[m] < g) l = m + 1; else h = m; } start = l; }
    { int l = 0, h = NN; while (l < h) { int m = (l + h) >> 1; if (batch[m] < g + 1) l = m + 1; else h = m; } end = l; }
    int cnt = end - start;
    float inv = 1.0f / (float)(cnt > 0 ? cnt : 1);
    float4 v = ((const float4*)(gsum + (size_t)g * 768))[t];
    float4 o; o.x = v.x * inv; o.y = v.y * inv; o.z = v.z * inv; o.w = v.w * inv;
    ((float4*)(graph_embed + (size_t)g * 768))[t] = o;
}

// ---------------------------------------------------------------------------
extern "C" void kernel_launch(void* const* d_in, const int* in_sizes, int n_in,
                              void* d_out, int out_size, void* d_ws, size_t ws_size,
                              hipStream_t stream) {
    const float* x     = (const float*)d_in[0];  // [N, 256]
    const int*   ei    = (const int*)d_in[1];    // [2, E]
    const int*   batch = (const int*)d_in[2];    // [N] (sorted)
    const float* Ws1   = (const float*)d_in[3];  // [L, 256, 256]
    const float* bs1   = (const float*)d_in[4];  // [L, 256]
    const float* Ws2   = (const float*)d_in[5];  // [L, 256, 256]
    const float* bs2   = (const float*)d_in[6];  // [L, 256]

    float* out         = (float*)d_out;
    float* graph_embed = out;                     // [G, 768]
    float* node_embed  = out + (size_t)GG * 768;  // [N, 768]

    // Workspace (re-poisoned before every call; fully rebuilt here).
    // h double-buffered: fused kernel reads h(l-1) while writing h(l).
    _Float16* h16   = (_Float16*)d_ws;                  // [MPAD, 256]
    _Float16* h_alt = h16 + (size_t)MPAD * DD;          // [MPAD, 256]
    _Float16* Wp    = h_alt + (size_t)MPAD * DD;        // 6 * 65536 halfs
    float* gsum     = (float*)(Wp + (size_t)6 * 65536); // [G, 768]
    int* cursor     = (int*)(gsum + (size_t)GG * 768);  // [N] (also deg)
    int* bsum       = cursor + NN;                      // [64]
    int* csr_src    = bsum + 64;                        // [E]
    int* row_ptr    = csr_src + EE;                     // [N+1]

    const int* src = ei;       // edge_index[0]
    const int* dst = ei + EE;  // edge_index[1]

    const int NB = (NN + 1023) / 1024;  // 49 scan blocks

    // x -> fp16, pack weights
    k_convert<<<(NN * DD / 4 + 255) / 256, 256, 0, stream>>>(x, h16);
    k_wpack<<<192, 256, 0, stream>>>(Ws1, Ws2, Wp);

    // Zero gsum + cursor + bsum in one contiguous memset
    hipMemsetAsync(gsum, 0, (size_t)GG * 768 * 4 + (size_t)NN * 4 + 64 * 4, stream);

    // Build CSR (dst -> list of src)
    k_hist<<<(EE + 255) / 256, 256, 0, stream>>>(dst, cursor, EE);
    k_scan1<<<NB, 1024, 0, stream>>>(cursor, row_ptr, bsum, NN);
    k_scan2<<<1, 64, 0, stream>>>(bsum, NB, row_ptr + NN);
    k_scan3<<<NB, 1024, 0, stream>>>(row_ptr, bsum, cursor, NN);
    k_scatter<<<(EE + 255) / 256, 256, 0, stream>>>(src, dst, cursor, csr_src, EE);

    for (int l = 0; l < LL; ++l) {
        const _Float16* hin = (l & 1) ? h_alt : h16;
        _Float16*       hout = (l & 1) ? h16 : h_alt;
        k_mlp<<<MPAD / 64, 256, 0, stream>>>(
            hin, row_ptr, csr_src, batch,
            Wp + (size_t)(2 * l + 0) * 65536, bs1 + (size_t)l * DD,
            Wp + (size_t)(2 * l + 1) * 65536, bs2 + (size_t)l * DD,
            hout, node_embed + (size_t)l * DD, gsum + (size_t)l * DD);
    }

    k_pool_final<<<GG, 192, 0, stream>>>(gsum, batch, graph_embed);
}

// Round 2
// 635.789 us; speedup vs baseline: 1.1175x; 1.1175x over previous
//
#include <hip/hip_runtime.h>

// Problem constants (match reference setup_inputs)
#define NN 50000
#define EE 800000
#define DD 256
#define LL 3
#define GG 512
#define MPAD 50048  // 782 * 64, GEMM row-tile padding

typedef __attribute__((ext_vector_type(4))) _Float16 half4;
typedef __attribute__((ext_vector_type(8))) _Float16 half8;
typedef __attribute__((ext_vector_type(16))) float floatx16;

// ---------------------------------------------------------------------------
// fp32 -> fp16 convert of x (one-time; h lives in fp16 from then on).
// ---------------------------------------------------------------------------
__global__ void k_convert(const float* __restrict__ x, _Float16* __restrict__ h16) {
    int i = blockIdx.x * 256 + threadIdx.x;  // float4 groups
    if (i >= NN * DD / 4) return;
    float4 v = ((const float4*)x)[i];
    half4 o;
    o.x = (_Float16)v.x; o.y = (_Float16)v.y; o.z = (_Float16)v.z; o.w = (_Float16)v.w;
    ((half4*)h16)[i] = o;
}

// ---------------------------------------------------------------------------
// CSR build: histogram -> 3-kernel parallel scan -> scatter
// ---------------------------------------------------------------------------
__global__ void k_hist(const int* __restrict__ dst, int* __restrict__ deg, int e) {
    int i = blockIdx.x * blockDim.x + threadIdx.x;
    if (i < e) atomicAdd(&deg[dst[i]], 1);
}

__global__ void k_scan1(const int* __restrict__ deg, int* __restrict__ rp,
                        int* __restrict__ bsum, int n) {
    __shared__ int s[1024];
    int t = threadIdx.x;
    int i = blockIdx.x * 1024 + t;
    int v = (i < n) ? deg[i] : 0;
    s[t] = v;
    __syncthreads();
    for (int off = 1; off < 1024; off <<= 1) {
        int tmp = (t >= off) ? s[t - off] : 0;
        __syncthreads();
        s[t] += tmp;
        __syncthreads();
    }
    if (i < n) rp[i] = s[t] - v;          // local exclusive
    if (t == 1023) bsum[blockIdx.x] = s[1023];
}

__global__ void k_scan2(int* __restrict__ bsum, int nb, int* __restrict__ total_out) {
    int lane = threadIdx.x & 63;
    int v = (lane < nb) ? bsum[lane] : 0;
    int orig = v;
    for (int off = 1; off < 64; off <<= 1) {
        int u = __shfl_up(v, off);
        if (lane >= off) v += u;
    }
    if (lane < nb) bsum[lane] = v - orig;  // exclusive block offsets
    if (lane == 63) *total_out = v;        // grand total -> row_ptr[N]
}

__global__ void k_scan3(int* __restrict__ rp, const int* __restrict__ bsum,
                        int* __restrict__ cursor, int n) {
    int i = blockIdx.x * 1024 + threadIdx.x;
    if (i < n) {
        int v = rp[i] + bsum[blockIdx.x];
        rp[i] = v;
        cursor[i] = v;
    }
}

__global__ void k_scatter(const int* __restrict__ src, const int* __restrict__ dst,
                          int* __restrict__ cursor, int* __restrict__ csr_src, int e) {
    int i = blockIdx.x * blockDim.x + threadIdx.x;
    if (i < e) {
        int d = dst[i];
        int pos = atomicAdd(&cursor[d], 1);
        csr_src[pos] = src[i];
    }
}

// ---------------------------------------------------------------------------
// Pre-pack W (fp32 [256,256], k-major) into fp16 MFMA B-fragments for
// mfma_f32_32x32x16_f16. Fragment (ks,nt): lane l holds
// B[ks*16 + (l>>5)*8 + j][nt*32 + (l&31)], j=0..7, 16B contiguous per lane.
// ---------------------------------------------------------------------------
__global__ void k_wpack(const float* __restrict__ Ws1, const float* __restrict__ Ws2,
                        _Float16* __restrict__ Wp) {
    int tid  = blockIdx.x * 256 + threadIdx.x;  // 6*16*8*64 = 49152
    int lane = tid & 63;
    int nt   = (tid >> 6) & 7;
    int ks   = (tid >> 9) & 15;
    int w    = tid >> 13;
    if (w >= 6) return;
    int l = w >> 1, s = w & 1;
    const float* W = (s == 0 ? Ws1 : Ws2) + (size_t)l * DD * DD;
    int kbase = ks * 16 + (lane >> 5) * 8;
    int n     = nt * 32 + (lane & 31);
    half8 hi;
#pragma unroll
    for (int j = 0; j < 8; ++j) hi[j] = (_Float16)W[(size_t)(kbase + j) * DD + n];
    ((half8*)Wp)[(((size_t)w * 16 + ks) * 8 + nt) * 64 + lane] = hi;
}

// ---------------------------------------------------------------------------
// Aggregation: agg[n] = h[n] + sum_{j->n} h[j]. One wave per node, 4 nodes
// per 256-thread block. Latency structure vs round-1's fused gather:
//   - the block's contiguous CSR segment (row_ptr[n0]..row_ptr[n0+4]) is
//     cooperatively staged into LDS first, so per-row processing has NO
//     dependent global index loads on its critical path;
//   - row loads are issued 16-deep (v[16] in flight, ~32 VGPRs), then
//     accumulated, so a deg-16 node pays ~one memory-latency wait;
//   - grid is 12500 blocks -> full occupancy for latency hiding.
// cnt > 1024 falls back to a global-index path (P ~ 0 for Poisson(64)).
// ---------------------------------------------------------------------------
__global__ __launch_bounds__(256) void k_gather(
        const _Float16* __restrict__ h,
        const int* __restrict__ row_ptr,
        const int* __restrict__ csr_src,
        _Float16* __restrict__ agg) {
    __shared__ int eidx[1024];
    __shared__ int rp_s[5];
    int t = threadIdx.x, lane = t & 63, w = t >> 6;
    int n0 = blockIdx.x * 4;
    if (t < 5) {
        int nn = n0 + t;
        if (nn > NN) nn = NN;
        rp_s[t] = row_ptr[nn];
    }
    __syncthreads();
    int beg0 = rp_s[0];
    int cnt  = rp_s[4] - beg0;
    for (int i = t; i < cnt && i < 1024; i += 256) eidx[i] = csr_src[beg0 + i];
    __syncthreads();

    int n = n0 + w;
    if (n >= NN) return;
    int beg = rp_s[w] - beg0, end = rp_s[w + 1] - beg0;
    const half4* hp = (const half4*)h;
    half4 acc = hp[(size_t)n * 64 + lane];

    if (cnt <= 1024) {
        // fast path: indices from LDS
        int j = beg;
        for (; j + 16 <= end; j += 16) {
            half4 v[16];
#pragma unroll
            for (int u = 0; u < 16; ++u) {
                int s = eidx[j + u];
                v[u] = hp[(size_t)s * 64 + lane];
            }
#pragma unroll
            for (int u = 0; u < 16; ++u) acc += v[u];
        }
        if (j + 8 <= end) {
            half4 v[8];
#pragma unroll
            for (int u = 0; u < 8; ++u) {
                int s = eidx[j + u];
                v[u] = hp[(size_t)s * 64 + lane];
            }
#pragma unroll
            for (int u = 0; u < 8; ++u) acc += v[u];
            j += 8;
        }
        if (j + 4 <= end) {
            half4 v[4];
#pragma unroll
            for (int u = 0; u < 4; ++u) {
                int s = eidx[j + u];
                v[u] = hp[(size_t)s * 64 + lane];
            }
            acc += v[0]; acc += v[1]; acc += v[2]; acc += v[3];
            j += 4;
        }
        for (; j < end; ++j) {
            int s = eidx[j];
            acc += hp[(size_t)s * 64 + lane];
        }
    } else {
        // rare fallback: indices from global
        int j = beg;
        for (; j + 4 <= end; j += 4) {
            int s0 = csr_src[beg0 + j + 0];
            int s1 = csr_src[beg0 + j + 1];
            int s2 = csr_src[beg0 + j + 2];
            int s3 = csr_src[beg0 + j + 3];
            half4 v0 = hp[(size_t)s0 * 64 + lane];
            half4 v1 = hp[(size_t)s1 * 64 + lane];
            half4 v2 = hp[(size_t)s2 * 64 + lane];
            half4 v3 = hp[(size_t)s3 * 64 + lane];
            acc += v0; acc += v1; acc += v2; acc += v3;
        }
        for (; j < end; ++j) {
            int s = csr_src[beg0 + j];
            acc += hp[(size_t)s * 64 + lane];
        }
    }
    ((half4*)(agg + (size_t)n * DD))[lane] = acc;
}

// ---------------------------------------------------------------------------
// Fused MLP + pool-accumulate: h_out = relu(relu(A@W1+b1)@W2+b2).
// Block: 256 threads = 4 waves, 64-row x 256-col tile; wave (wm,wn) owns the
// 32-row x 128-col quadrant (4 n-tiles of mfma_f32_32x32x16_f16).
// GEMM1 A-fragments come straight from global agg; t round-trips through
// LDS fp16 with XOR swizzle. Epilogue 2 additionally accumulates per-graph
// column sums (batch sorted -> a wave's 32 rows span 1-2 graphs) into gsum.
// ---------------------------------------------------------------------------
__global__ __launch_bounds__(256) void k_mlp(
        const _Float16* __restrict__ A,    // agg16 [MPAD, 256]
        const int* __restrict__ batch,
        const _Float16* __restrict__ Wp1, const float* __restrict__ b1,
        const _Float16* __restrict__ Wp2, const float* __restrict__ b2,
        _Float16* __restrict__ Hout,       // h16 [MPAD, 256]
        float* __restrict__ Fout,          // node_embed + l*256, row stride 768
        float* __restrict__ Gout) {        // gsum + l*256, row stride 768
    __shared__ _Float16 t_lds[64 * 256];   // 32 KB
    __shared__ int batch_s[64];
    int t    = threadIdx.x;
    int lane = t & 63;
    int w    = t >> 6;
    int wm   = w >> 1, wn = w & 1;
    int r0   = blockIdx.x * 64;

    if (t < 64) {
        int r = r0 + t;
        batch_s[t] = (r < NN) ? batch[r] : 0x7fffffff;
    }

    // ---- GEMM1: acc = A @ W1 (A fragments direct from global) ----
    int arow = r0 + wm * 32 + (lane & 31);
    const half8* baseA = (const half8*)(A + (size_t)arow * DD) + (lane >> 5);
    const half8* B1    = (const half8*)Wp1;

    floatx16 acc[4];
#pragma unroll
    for (int nt = 0; nt < 4; ++nt)
#pragma unroll
        for (int i = 0; i < 16; ++i) acc[nt][i] = 0.0f;

#pragma unroll 4
    for (int ks = 0; ks < 16; ++ks) {
        half8 a = baseA[ks * 2];
#pragma unroll
        for (int nt = 0; nt < 4; ++nt) {
            half8 b = B1[(size_t)(ks * 8 + wn * 4 + nt) * 64 + lane];
            acc[nt] = __builtin_amdgcn_mfma_f32_32x32x16_f16(a, b, acc[nt], 0, 0, 0);
        }
    }

    // ---- epilogue 1: t = relu(acc + b1) -> LDS (fp16, swizzled) ----
#pragma unroll
    for (int nt = 0; nt < 4; ++nt) {
        int c  = wn * 128 + nt * 32 + (lane & 31);
        float bv = b1[c];
#pragma unroll
        for (int reg = 0; reg < 16; ++reg) {
            int lr = wm * 32 + (reg & 3) + 8 * (reg >> 2) + 4 * (lane >> 5);
            float v = fmaxf(acc[nt][reg] + bv, 0.0f);
            t_lds[lr * 256 + ((((c >> 3) ^ (lr & 7)) << 3) | (c & 7))] = (_Float16)v;
        }
    }
    __syncthreads();

    // ---- GEMM2: acc2 = t @ W2 (A fragments from swizzled LDS) ----
    const half8* B2 = (const half8*)Wp2;
    int r = wm * 32 + (lane & 31);
    floatx16 acc2[4];
#pragma unroll
    for (int nt = 0; nt < 4; ++nt)
#pragma unroll
        for (int i = 0; i < 16; ++i) acc2[nt][i] = 0.0f;

#pragma unroll 4
    for (int ks = 0; ks < 16; ++ks) {
        int kblk = ks * 2 + (lane >> 5);
        half8 a = *(const half8*)&t_lds[r * 256 + ((kblk ^ (r & 7)) << 3)];
#pragma unroll
        for (int nt = 0; nt < 4; ++nt) {
            half8 b = B2[(size_t)(ks * 8 + wn * 4 + nt) * 64 + lane];
            acc2[nt] = __builtin_amdgcn_mfma_f32_32x32x16_f16(a, b, acc2[nt], 0, 0, 0);
        }
    }

    // ---- epilogue 2: h = relu(acc2 + b2) -> fp16 h16 + fp32 node_embed ----
    const int rbase = wm * 32 + 4 * (lane >> 5);
#pragma unroll
    for (int nt = 0; nt < 4; ++nt) {
        int col = wn * 128 + nt * 32 + (lane & 31);
        float bv = b2[col];
#pragma unroll
        for (int reg = 0; reg < 16; ++reg) {
            int rowid = rbase + (reg & 3) + 8 * (reg >> 2);
            int row = r0 + rowid;
            if (row < NN) {
                float v = fmaxf(acc2[nt][reg] + bv, 0.0f);
                Hout[(size_t)row * DD + col] = (_Float16)v;
                Fout[(size_t)row * 768 + col] = v;
            }
        }
    }

    // ---- pool accumulate: per-graph column sums (batch sorted; a wave's
    //      32 rows span ~1-2 graphs). Cross-half merge by shfl_xor(32),
    //      then one atomicAdd per (graph, col) partial.
    int lastid = NN - 1 - r0 - wm * 32;
    if (lastid >= 0) {
        if (lastid > 31) lastid = 31;
        int g0 = batch_s[wm * 32];
        int g1 = batch_s[wm * 32 + lastid];
        for (int g = g0; g <= g1; ++g) {
#pragma unroll
            for (int nt = 0; nt < 4; ++nt) {
                int col = wn * 128 + nt * 32 + (lane & 31);
                float bv = b2[col];
                float s = 0.0f;
#pragma unroll
                for (int reg = 0; reg < 16; ++reg) {
                    int rowid = rbase + (reg & 3) + 8 * (reg >> 2);
                    if (batch_s[rowid] == g)
                        s += fmaxf(acc2[nt][reg] + bv, 0.0f);
                }
                s += __shfl_xor(s, 32);
                if (lane < 32)
                    atomicAdd(&Gout[(size_t)g * 768 + col], s);
            }
        }
    }
}

// ---------------------------------------------------------------------------
// Finalize pool: graph_embed = gsum / count. One block per graph.
// ---------------------------------------------------------------------------
__global__ void k_pool_final(const float* __restrict__ gsum,
                             const int* __restrict__ batch,
                             float* __restrict__ graph_embed) {
    int g = blockIdx.x;
    int t = threadIdx.x;  // 0..191
    int start, end;
    { int l = 0, h = NN; while (l < h) { int m = (l + h) >> 1; if (batch[m] < g) l = m + 1; else h = m; } start = l; }
    { int l = 0, h = NN; while (l < h) { int m = (l + h) >> 1; if (batch[m] < g + 1) l = m + 1; else h = m; } end = l; }
    int cnt = end - start;
    float inv = 1.0f / (float)(cnt > 0 ? cnt : 1);
    float4 v = ((const float4*)(gsum + (size_t)g * 768))[t];
    float4 o; o.x = v.x * inv; o.y = v.y * inv; o.z = v.z * inv; o.w = v.w * inv;
    ((float4*)(graph_embed + (size_t)g * 768))[t] = o;
}

// ---------------------------------------------------------------------------
extern "C" void kernel_launch(void* const* d_in, const int* in_sizes, int n_in,
                              void* d_out, int out_size, void* d_ws, size_t ws_size,
                              hipStream_t stream) {
    const float* x     = (const float*)d_in[0];  // [N, 256]
    const int*   ei    = (const int*)d_in[1];    // [2, E]
    const int*   batch = (const int*)d_in[2];    // [N] (sorted)
    const float* Ws1   = (const float*)d_in[3];  // [L, 256, 256]
    const float* bs1   = (const float*)d_in[4];  // [L, 256]
    const float* Ws2   = (const float*)d_in[5];  // [L, 256, 256]
    const float* bs2   = (const float*)d_in[6];  // [L, 256]

    float* out         = (float*)d_out;
    float* graph_embed = out;                     // [G, 768]
    float* node_embed  = out + (size_t)GG * 768;  // [N, 768]

    // Workspace (re-poisoned before every call; fully rebuilt here)
    _Float16* h16   = (_Float16*)d_ws;                  // [MPAD, 256]
    _Float16* agg16 = h16 + (size_t)MPAD * DD;          // [MPAD, 256]
    _Float16* Wp    = agg16 + (size_t)MPAD * DD;        // 6 * 65536 halfs
    float* gsum     = (float*)(Wp + (size_t)6 * 65536); // [G, 768]
    int* cursor     = (int*)(gsum + (size_t)GG * 768);  // [N] (also deg)
    int* bsum       = cursor + NN;                      // [64]
    int* csr_src    = bsum + 64;                        // [E]
    int* row_ptr    = csr_src + EE;                     // [N+1]

    const int* src = ei;       // edge_index[0]
    const int* dst = ei + EE;  // edge_index[1]

    const int NB = (NN + 1023) / 1024;  // 49 scan blocks

    // x -> fp16, pack weights
    k_convert<<<(NN * DD / 4 + 255) / 256, 256, 0, stream>>>(x, h16);
    k_wpack<<<192, 256, 0, stream>>>(Ws1, Ws2, Wp);

    // Zero gsum + cursor + bsum in one contiguous memset
    hipMemsetAsync(gsum, 0, (size_t)GG * 768 * 4 + (size_t)NN * 4 + 64 * 4, stream);

    // Build CSR (dst -> list of src)
    k_hist<<<(EE + 255) / 256, 256, 0, stream>>>(dst, cursor, EE);
    k_scan1<<<NB, 1024, 0, stream>>>(cursor, row_ptr, bsum, NN);
    k_scan2<<<1, 64, 0, stream>>>(bsum, NB, row_ptr + NN);
    k_scan3<<<NB, 1024, 0, stream>>>(row_ptr, bsum, cursor, NN);
    k_scatter<<<(EE + 255) / 256, 256, 0, stream>>>(src, dst, cursor, csr_src, EE);

    for (int l = 0; l < LL; ++l) {
        // agg = h + segment_sum(h[src], dst)
        k_gather<<<(NN + 3) / 4, 256, 0, stream>>>(h16, row_ptr, csr_src, agg16);
        // h = relu(relu(agg@W1+b1)@W2+b2) -> h16 + node_embed + gsum partials
        k_mlp<<<MPAD / 64, 256, 0, stream>>>(
            agg16, batch,
            Wp + (size_t)(2 * l + 0) * 65536, bs1 + (size_t)l * DD,
            Wp + (size_t)(2 * l + 1) * 65536, bs2 + (size_t)l * DD,
            h16, node_embed + (size_t)l * DD, gsum + (size_t)l * DD);
    }

    k_pool_final<<<GG, 192, 0, stream>>>(gsum, batch, graph_embed);
}

// Round 3
// 618.651 us; speedup vs baseline: 1.1485x; 1.0277x over previous
//
#include <hip/hip_runtime.h>

// Problem constants (match reference setup_inputs)
#define NN 50000
#define EE 800000
#define DD 256
#define LL 3
#define GG 512
#define MPAD 50048  // 782 * 64, GEMM row-tile padding

typedef __attribute__((ext_vector_type(4))) _Float16 half4;
typedef __attribute__((ext_vector_type(8))) _Float16 half8;
typedef __attribute__((ext_vector_type(16))) float floatx16;

// ---------------------------------------------------------------------------
// Fused prep kernel (independent work, split by blockIdx range):
//   [0, 12500)        : x fp32 -> fp16 convert
//   [12500, 12692)    : weight pack (192 blocks)
//   [12692, 15817)    : degree histogram (3125 blocks)
// Removes two head-of-graph serialization points; hist overlaps convert.
// ---------------------------------------------------------------------------
#define CONV_B 12500
#define WPK_B  192
#define HIST_B 3125

__global__ void k_prep(const float* __restrict__ x, _Float16* __restrict__ h16,
                       const float* __restrict__ Ws1, const float* __restrict__ Ws2,
                       _Float16* __restrict__ Wp,
                       const int* __restrict__ dst, int* __restrict__ deg) {
    int b = blockIdx.x;
    if (b < CONV_B) {
        int i = b * 256 + threadIdx.x;  // float4 groups, NN*DD/4 = 3.2M
        if (i >= NN * DD / 4) return;
        float4 v = ((const float4*)x)[i];
        half4 o;
        o.x = (_Float16)v.x; o.y = (_Float16)v.y; o.z = (_Float16)v.z; o.w = (_Float16)v.w;
        ((half4*)h16)[i] = o;
    } else if (b < CONV_B + WPK_B) {
        // Pre-pack W (fp32 [256,256], k-major) into fp16 MFMA B-fragments for
        // mfma_f32_32x32x16_f16. Fragment (ks,nt): lane l holds
        // B[ks*16 + (l>>5)*8 + j][nt*32 + (l&31)], j=0..7.
        int tid  = (b - CONV_B) * 256 + threadIdx.x;  // 6*16*8*64 = 49152
        int lane = tid & 63;
        int nt   = (tid >> 6) & 7;
        int ks   = (tid >> 9) & 15;
        int w    = tid >> 13;
        if (w >= 6) return;
        int l = w >> 1, s = w & 1;
        const float* W = (s == 0 ? Ws1 : Ws2) + (size_t)l * DD * DD;
        int kbase = ks * 16 + (lane >> 5) * 8;
        int n     = nt * 32 + (lane & 31);
        half8 hi;
#pragma unroll
        for (int j = 0; j < 8; ++j) hi[j] = (_Float16)W[(size_t)(kbase + j) * DD + n];
        ((half8*)Wp)[(((size_t)w * 16 + ks) * 8 + nt) * 64 + lane] = hi;
    } else {
        int i = (b - CONV_B - WPK_B) * 256 + threadIdx.x;
        if (i < EE) atomicAdd(&deg[dst[i]], 1);
    }
}

// ---------------------------------------------------------------------------
// CSR build: 3-kernel parallel scan -> scatter (histogram is in k_prep)
// ---------------------------------------------------------------------------
__global__ void k_scan1(const int* __restrict__ deg, int* __restrict__ rp,
                        int* __restrict__ bsum, int n) {
    __shared__ int s[1024];
    int t = threadIdx.x;
    int i = blockIdx.x * 1024 + t;
    int v = (i < n) ? deg[i] : 0;
    s[t] = v;
    __syncthreads();
    for (int off = 1; off < 1024; off <<= 1) {
        int tmp = (t >= off) ? s[t - off] : 0;
        __syncthreads();
        s[t] += tmp;
        __syncthreads();
    }
    if (i < n) rp[i] = s[t] - v;          // local exclusive
    if (t == 1023) bsum[blockIdx.x] = s[1023];
}

__global__ void k_scan2(int* __restrict__ bsum, int nb, int* __restrict__ total_out) {
    int lane = threadIdx.x & 63;
    int v = (lane < nb) ? bsum[lane] : 0;
    int orig = v;
    for (int off = 1; off < 64; off <<= 1) {
        int u = __shfl_up(v, off);
        if (lane >= off) v += u;
    }
    if (lane < nb) bsum[lane] = v - orig;  // exclusive block offsets
    if (lane == 63) *total_out = v;        // grand total -> row_ptr[N]
}

__global__ void k_scan3(int* __restrict__ rp, const int* __restrict__ bsum,
                        int* __restrict__ cursor, int n) {
    int i = blockIdx.x * 1024 + threadIdx.x;
    if (i < n) {
        int v = rp[i] + bsum[blockIdx.x];
        rp[i] = v;
        cursor[i] = v;
    }
}

__global__ void k_scatter(const int* __restrict__ src, const int* __restrict__ dst,
                          int* __restrict__ cursor, int* __restrict__ csr_src, int e) {
    int i = blockIdx.x * blockDim.x + threadIdx.x;
    if (i < e) {
        int d = dst[i];
        int pos = atomicAdd(&cursor[d], 1);
        csr_src[pos] = src[i];
    }
}

// ---------------------------------------------------------------------------
// Aggregation: agg[n] = h[n] + sum_{j->n} h[j]. One wave per node, 4 nodes
// per 256-thread block. vs round 2:
//   - half8 (16 B/lane) row loads: 32 lanes fetch a full 512 B row, so the
//     64-lane wave processes TWO edges per load instruction (lanes 0-31 take
//     even-indexed edges, lanes 32-63 odd). Halves VMEM instruction count.
//   - 8 loads in flight = 16 edges/batch; predicated static-indexed tail
//     (no scratch arrays, no serial dependent chain).
//   - block's CSR segment staged in LDS first (no dependent global index
//     loads on the row critical path).
// Final cross-half fold via shfl_xor(32); lanes 0-31 store the row.
// ---------------------------------------------------------------------------
__global__ __launch_bounds__(256) void k_gather(
        const _Float16* __restrict__ h,
        const int* __restrict__ row_ptr,
        const int* __restrict__ csr_src,
        _Float16* __restrict__ agg) {
    __shared__ int eidx[1024];
    __shared__ int rp_s[5];
    int t = threadIdx.x, lane = t & 63, w = t >> 6;
    int n0 = blockIdx.x * 4;
    if (t < 5) {
        int nn = n0 + t;
        if (nn > NN) nn = NN;
        rp_s[t] = row_ptr[nn];
    }
    __syncthreads();
    int beg0 = rp_s[0];
    int cnt  = rp_s[4] - beg0;
    for (int i = t; i < cnt && i < 1024; i += 256) eidx[i] = csr_src[beg0 + i];
    __syncthreads();

    int n = n0 + w;
    if (n >= NN) return;
    int beg = rp_s[w] - beg0, end = rp_s[w + 1] - beg0;
    int hf = lane >> 5;   // 0: own row + even edges; 1: odd edges
    int cl = lane & 31;   // column group: cols [cl*8, cl*8+8)
    const half8* hp = (const half8*)h;  // row n = hp[n*32 + cl]

    half8 acc;
#pragma unroll
    for (int i = 0; i < 8; ++i) acc[i] = (_Float16)0;
    if (hf == 0) acc = hp[(size_t)n * 32 + cl];

    if (cnt <= 1024) {
        int k = beg;
        for (; k + 16 <= end; k += 16) {
            half8 v[8];
#pragma unroll
            for (int u = 0; u < 8; ++u) {
                int s = eidx[k + 2 * u + hf];
                v[u] = hp[(size_t)s * 32 + cl];
            }
#pragma unroll
            for (int u = 0; u < 8; ++u) acc += v[u];
        }
        // tail < 16 edges: predicated, static-indexed, loads all in flight
        if (k < end) {
#pragma unroll
            for (int u = 0; u < 8; ++u) {
                int e = k + 2 * u + hf;
                half8 v;
#pragma unroll
                for (int i = 0; i < 8; ++i) v[i] = (_Float16)0;
                if (e < end) v = hp[(size_t)eidx[e] * 32 + cl];
                acc += v;
            }
        }
    } else {
        // rare fallback: indices from global
        int k = beg;
        for (; k + 16 <= end; k += 16) {
            half8 v[8];
#pragma unroll
            for (int u = 0; u < 8; ++u) {
                int s = csr_src[beg0 + k + 2 * u + hf];
                v[u] = hp[(size_t)s * 32 + cl];
            }
#pragma unroll
            for (int u = 0; u < 8; ++u) acc += v[u];
        }
        if (k < end) {
#pragma unroll
            for (int u = 0; u < 8; ++u) {
                int e = k + 2 * u + hf;
                half8 v;
#pragma unroll
                for (int i = 0; i < 8; ++i) v[i] = (_Float16)0;
                if (e < end) v = hp[(size_t)csr_src[beg0 + e] * 32 + cl];
                acc += v;
            }
        }
    }

    // fold odd-half into even-half (16 B = int4 via 4 shfl_xor)
    int4 ai = *(int4*)&acc;
    int4 bi;
    bi.x = __shfl_xor(ai.x, 32);
    bi.y = __shfl_xor(ai.y, 32);
    bi.z = __shfl_xor(ai.z, 32);
    bi.w = __shfl_xor(ai.w, 32);
    acc += *(half8*)&bi;
    if (hf == 0) ((half8*)(agg + (size_t)n * DD))[cl] = acc;
}

// ---------------------------------------------------------------------------
// Fused MLP + pool-accumulate: h_out = relu(relu(A@W1+b1)@W2+b2).
// Block: 256 threads = 4 waves, 64-row x 256-col tile; wave (wm,wn) owns the
// 32-row x 128-col quadrant (4 n-tiles of mfma_f32_32x32x16_f16).
// GEMM1 A-fragments come straight from global agg; t round-trips through
// LDS fp16 with XOR swizzle. Fout (node_embed) written with NONTEMPORAL
// stores: it is never re-read by any kernel, and keeping it out of L2
// preserves h rows for the next layer's gather.
// ---------------------------------------------------------------------------
__global__ __launch_bounds__(256) void k_mlp(
        const _Float16* __restrict__ A,    // agg16 [MPAD, 256]
        const int* __restrict__ batch,
        const _Float16* __restrict__ Wp1, const float* __restrict__ b1,
        const _Float16* __restrict__ Wp2, const float* __restrict__ b2,
        _Float16* __restrict__ Hout,       // h16 [MPAD, 256]
        float* __restrict__ Fout,          // node_embed + l*256, row stride 768
        float* __restrict__ Gout) {        // gsum + l*256, row stride 768
    __shared__ _Float16 t_lds[64 * 256];   // 32 KB
    __shared__ int batch_s[64];
    int t    = threadIdx.x;
    int lane = t & 63;
    int w    = t >> 6;
    int wm   = w >> 1, wn = w & 1;
    int r0   = blockIdx.x * 64;

    if (t < 64) {
        int r = r0 + t;
        batch_s[t] = (r < NN) ? batch[r] : 0x7fffffff;
    }

    // ---- GEMM1: acc = A @ W1 (A fragments direct from global) ----
    int arow = r0 + wm * 32 + (lane & 31);
    const half8* baseA = (const half8*)(A + (size_t)arow * DD) + (lane >> 5);
    const half8* B1    = (const half8*)Wp1;

    floatx16 acc[4];
#pragma unroll
    for (int nt = 0; nt < 4; ++nt)
#pragma unroll
        for (int i = 0; i < 16; ++i) acc[nt][i] = 0.0f;

#pragma unroll 4
    for (int ks = 0; ks < 16; ++ks) {
        half8 a = baseA[ks * 2];
#pragma unroll
        for (int nt = 0; nt < 4; ++nt) {
            half8 b = B1[(size_t)(ks * 8 + wn * 4 + nt) * 64 + lane];
            acc[nt] = __builtin_amdgcn_mfma_f32_32x32x16_f16(a, b, acc[nt], 0, 0, 0);
        }
    }

    // ---- epilogue 1: t = relu(acc + b1) -> LDS (fp16, swizzled) ----
#pragma unroll
    for (int nt = 0; nt < 4; ++nt) {
        int c  = wn * 128 + nt * 32 + (lane & 31);
        float bv = b1[c];
#pragma unroll
        for (int reg = 0; reg < 16; ++reg) {
            int lr = wm * 32 + (reg & 3) + 8 * (reg >> 2) + 4 * (lane >> 5);
            float v = fmaxf(acc[nt][reg] + bv, 0.0f);
            t_lds[lr * 256 + ((((c >> 3) ^ (lr & 7)) << 3) | (c & 7))] = (_Float16)v;
        }
    }
    __syncthreads();

    // ---- GEMM2: acc2 = t @ W2 (A fragments from swizzled LDS) ----
    const half8* B2 = (const half8*)Wp2;
    int r = wm * 32 + (lane & 31);
    floatx16 acc2[4];
#pragma unroll
    for (int nt = 0; nt < 4; ++nt)
#pragma unroll
        for (int i = 0; i < 16; ++i) acc2[nt][i] = 0.0f;

#pragma unroll 4
    for (int ks = 0; ks < 16; ++ks) {
        int kblk = ks * 2 + (lane >> 5);
        half8 a = *(const half8*)&t_lds[r * 256 + ((kblk ^ (r & 7)) << 3)];
#pragma unroll
        for (int nt = 0; nt < 4; ++nt) {
            half8 b = B2[(size_t)(ks * 8 + wn * 4 + nt) * 64 + lane];
            acc2[nt] = __builtin_amdgcn_mfma_f32_32x32x16_f16(a, b, acc2[nt], 0, 0, 0);
        }
    }

    // ---- epilogue 2: h = relu(acc2 + b2) -> fp16 h16 + fp32 node_embed ----
    const int rbase = wm * 32 + 4 * (lane >> 5);
#pragma unroll
    for (int nt = 0; nt < 4; ++nt) {
        int col = wn * 128 + nt * 32 + (lane & 31);
        float bv = b2[col];
#pragma unroll
        for (int reg = 0; reg < 16; ++reg) {
            int rowid = rbase + (reg & 3) + 8 * (reg >> 2);
            int row = r0 + rowid;
            if (row < NN) {
                float v = fmaxf(acc2[nt][reg] + bv, 0.0f);
                Hout[(size_t)row * DD + col] = (_Float16)v;
                __builtin_nontemporal_store(v, &Fout[(size_t)row * 768 + col]);
            }
        }
    }

    // ---- pool accumulate: per-graph column sums (batch sorted; a wave's
    //      32 rows span 1-2 graphs). Cross-half merge by shfl_xor(32),
    //      then one atomicAdd per (graph, col) partial.
    int lastid = NN - 1 - r0 - wm * 32;
    if (lastid >= 0) {
        if (lastid > 31) lastid = 31;
        int g0 = batch_s[wm * 32];
        int g1 = batch_s[wm * 32 + lastid];
        for (int g = g0; g <= g1; ++g) {
#pragma unroll
            for (int nt = 0; nt < 4; ++nt) {
                int col = wn * 128 + nt * 32 + (lane & 31);
                float bv = b2[col];
                float s = 0.0f;
#pragma unroll
                for (int reg = 0; reg < 16; ++reg) {
                    int rowid = rbase + (reg & 3) + 8 * (reg >> 2);
                    if (batch_s[rowid] == g)
                        s += fmaxf(acc2[nt][reg] + bv, 0.0f);
                }
                s += __shfl_xor(s, 32);
                if (lane < 32)
                    atomicAdd(&Gout[(size_t)g * 768 + col], s);
            }
        }
    }
}

// ---------------------------------------------------------------------------
// Finalize pool: graph_embed = gsum / count. One block per graph.
// ---------------------------------------------------------------------------
__global__ void k_pool_final(const float* __restrict__ gsum,
                             const int* __restrict__ batch,
                             float* __restrict__ graph_embed) {
    int g = blockIdx.x;
    int t = threadIdx.x;  // 0..191
    int start, end;
    { int l = 0, h = NN; while (l < h) { int m = (l + h) >> 1; if (batch[m] < g) l = m + 1; else h = m; } start = l; }
    { int l = 0, h = NN; while (l < h) { int m = (l + h) >> 1; if (batch[m] < g + 1) l = m + 1; else h = m; } end = l; }
    int cnt = end - start;
    float inv = 1.0f / (float)(cnt > 0 ? cnt : 1);
    float4 v = ((const float4*)(gsum + (size_t)g * 768))[t];
    float4 o; o.x = v.x * inv; o.y = v.y * inv; o.z = v.z * inv; o.w = v.w * inv;
    ((float4*)(graph_embed + (size_t)g * 768))[t] = o;
}

// ---------------------------------------------------------------------------
extern "C" void kernel_launch(void* const* d_in, const int* in_sizes, int n_in,
                              void* d_out, int out_size, void* d_ws, size_t ws_size,
                              hipStream_t stream) {
    const float* x     = (const float*)d_in[0];  // [N, 256]
    const int*   ei    = (const int*)d_in[1];    // [2, E]
    const int*   batch = (const int*)d_in[2];    // [N] (sorted)
    const float* Ws1   = (const float*)d_in[3];  // [L, 256, 256]
    const float* bs1   = (const float*)d_in[4];  // [L, 256]
    const float* Ws2   = (const float*)d_in[5];  // [L, 256, 256]
    const float* bs2   = (const float*)d_in[6];  // [L, 256]

    float* out         = (float*)d_out;
    float* graph_embed = out;                     // [G, 768]
    float* node_embed  = out + (size_t)GG * 768;  // [N, 768]

    // Workspace (re-poisoned before every call; fully rebuilt here)
    _Float16* h16   = (_Float16*)d_ws;                  // [MPAD, 256]
    _Float16* agg16 = h16 + (size_t)MPAD * DD;          // [MPAD, 256]
    _Float16* Wp    = agg16 + (size_t)MPAD * DD;        // 6 * 65536 halfs
    float* gsum     = (float*)(Wp + (size_t)6 * 65536); // [G, 768]
    int* cursor     = (int*)(gsum + (size_t)GG * 768);  // [N] (also deg)
    int* bsum       = cursor + NN;                      // [64]
    int* csr_src    = bsum + 64;                        // [E]
    int* row_ptr    = csr_src + EE;                     // [N+1]

    const int* src = ei;       // edge_index[0]
    const int* dst = ei + EE;  // edge_index[1]

    const int NB = (NN + 1023) / 1024;  // 49 scan blocks

    // Zero gsum + cursor + bsum in one contiguous memset (before k_prep hist!)
    hipMemsetAsync(gsum, 0, (size_t)GG * 768 * 4 + (size_t)NN * 4 + 64 * 4, stream);

    // convert + wpack + hist in one launch
    k_prep<<<CONV_B + WPK_B + HIST_B, 256, 0, stream>>>(x, h16, Ws1, Ws2, Wp, dst, cursor);

    // Finish CSR (dst -> list of src)
    k_scan1<<<NB, 1024, 0, stream>>>(cursor, row_ptr, bsum, NN);
    k_scan2<<<1, 64, 0, stream>>>(bsum, NB, row_ptr + NN);
    k_scan3<<<NB, 1024, 0, stream>>>(row_ptr, bsum, cursor, NN);
    k_scatter<<<(EE + 255) / 256, 256, 0, stream>>>(src, dst, cursor, csr_src, EE);

    for (int l = 0; l < LL; ++l) {
        // agg = h + segment_sum(h[src], dst)
        k_gather<<<(NN + 3) / 4, 256, 0, stream>>>(h16, row_ptr, csr_src, agg16);
        // h = relu(relu(agg@W1+b1)@W2+b2) -> h16 + node_embed + gsum partials
        k_mlp<<<MPAD / 64, 256, 0, stream>>>(
            agg16, batch,
            Wp + (size_t)(2 * l + 0) * 65536, bs1 + (size_t)l * DD,
            Wp + (size_t)(2 * l + 1) * 65536, bs2 + (size_t)l * DD,
            h16, node_embed + (size_t)l * DD, gsum + (size_t)l * DD);
    }

    k_pool_final<<<GG, 192, 0, stream>>>(gsum, batch, graph_embed);
}